// Round 1
// baseline (160.105 us; speedup 1.0000x reference)
//
#include <hip/hip_runtime.h>

#define D 64
#define K 512
#define ROWS_PER_BLOCK 64
#define WAVES 4
#define KCOLS_PER_WAVE (K / WAVES)     // 128
#define KG 8                           // columns per k-group
#define NGROUPS (KCOLS_PER_WAVE / KG)  // 16

// Main fused kernel: distances + argmin + quantize + straight-through out + loss partial.
// Layout: one block = 64 rows (x-vectors); 4 waves each scan a 128-column K-slice.
// lane = row  ->  x row lives in 64 VGPRs, loaded once.
// e columns are wave-uniform (readfirstlane'd base) -> scalar-pipe loads, VALU does pure FMA.
__global__ __launch_bounds__(256, 4) void vq_main(
    const float* __restrict__ x,
    const float* __restrict__ emb,
    float* __restrict__ out,
    float* __restrict__ lossAcc)
{
    __shared__ float s_enorm[K];
    __shared__ float s_min[WAVES * 64];
    __shared__ int   s_idx[WAVES * 64];
    __shared__ int   s_final[ROWS_PER_BLOCK];
    __shared__ float s_wsum[WAVES];

    const int t    = threadIdx.x;
    const int lane = t & 63;
    const int w    = t >> 6;
    const int r0   = blockIdx.x * ROWS_PER_BLOCK;
    const int row  = r0 + lane;

    // ---- load this lane's x row into registers (16x float4, L1-friendly) ----
    float rx[D];
    {
        const float4* xv = (const float4*)(x + (size_t)row * D);
        #pragma unroll
        for (int i = 0; i < D / 4; ++i) {
            float4 v = xv[i];
            rx[4*i+0] = v.x; rx[4*i+1] = v.y; rx[4*i+2] = v.z; rx[4*i+3] = v.w;
        }
    }
    float xn = 0.f;
    #pragma unroll
    for (int d = 0; d < D; ++d) xn = fmaf(rx[d], rx[d], xn);

    // ---- cooperative codebook norms into LDS (thread t -> columns 2t, 2t+1) ----
    {
        const int k0 = t * 2;
        float n0 = 0.f, n1 = 0.f;
        for (int d = 0; d < D; ++d) {
            float2 e2 = *(const float2*)(emb + (size_t)d * K + k0);
            n0 = fmaf(e2.x, e2.x, n0);
            n1 = fmaf(e2.y, e2.y, n1);
        }
        s_enorm[k0]     = n0;
        s_enorm[k0 + 1] = n1;
    }
    __syncthreads();

    // ---- main scan: this wave's 128 columns, 8 at a time ----
    float best = 3.4e38f;
    int   bidx = 0;
    const int wk0 = __builtin_amdgcn_readfirstlane(w * KCOLS_PER_WAVE);

    for (int g = 0; g < NGROUPS; ++g) {
        const int kb = wk0 + g * KG;     // wave-uniform
        const float* ep = emb + kb;
        float acc[KG];
        #pragma unroll
        for (int j = 0; j < KG; ++j) acc[j] = 0.f;

        #pragma unroll
        for (int d = 0; d < D; ++d) {
            const float* er = ep + (size_t)d * K;   // uniform address -> scalar loads
            #pragma unroll
            for (int j = 0; j < KG; ++j)
                acc[j] = fmaf(rx[d], er[j], acc[j]);
        }

        #pragma unroll
        for (int j = 0; j < KG; ++j) {
            // same formula as reference: (||x||^2 + ||e||^2) - 2*dot  -> same tie quantization
            float s = (xn + s_enorm[kb + j]) - 2.0f * acc[j];
            if (s < best) { best = s; bidx = kb + j; }   // strict < keeps lowest k on ties
        }
    }

    s_min[w * 64 + lane] = best;
    s_idx[w * 64 + lane] = bidx;
    __syncthreads();

    // ---- merge the 4 per-wave candidates (ascending wave order = ascending k) ----
    if (t < 64) {
        float b  = s_min[t];
        int   bi = s_idx[t];
        #pragma unroll
        for (int ww = 1; ww < WAVES; ++ww) {
            float c  = s_min[ww * 64 + t];
            int   ci = s_idx[ww * 64 + t];
            if (c < b) { b = c; bi = ci; }
        }
        s_final[t] = bi;
    }
    __syncthreads();

    // ---- epilogue: quantize, straight-through output, loss partial ----
    // tile has 64 rows x 64 d = 4096 elems = 1024 float4; thread t does f4 #t, t+256, ...
    float ls = 0.f;
    #pragma unroll
    for (int i = 0; i < 4; ++i) {
        int f  = t + 256 * i;
        int rr = f >> 4;      // row in tile
        int d4 = f & 15;      // float4 index within row
        int kq = s_final[rr];
        const float* eb = emb + kq;
        size_t gbase = ((size_t)(r0 + rr)) * D + (size_t)d4 * 4;
        float4 xv = *(const float4*)(x + gbase);
        float q0 = eb[(size_t)(d4 * 4 + 0) * K];
        float q1 = eb[(size_t)(d4 * 4 + 1) * K];
        float q2 = eb[(size_t)(d4 * 4 + 2) * K];
        float q3 = eb[(size_t)(d4 * 4 + 3) * K];
        float dx0 = q0 - xv.x, dx1 = q1 - xv.y, dx2 = q2 - xv.z, dx3 = q3 - xv.w;
        float4 o;
        o.x = xv.x + dx0;   // x + sg(q - x), matching reference arithmetic
        o.y = xv.y + dx1;
        o.z = xv.z + dx2;
        o.w = xv.w + dx3;
        *(float4*)(out + gbase) = o;
        ls += dx0 * dx0 + dx1 * dx1 + dx2 * dx2 + dx3 * dx3;
    }

    #pragma unroll
    for (int o = 32; o > 0; o >>= 1) ls += __shfl_xor(ls, o, 64);
    if (lane == 0) s_wsum[w] = ls;
    __syncthreads();
    if (t == 0) {
        float s = s_wsum[0] + s_wsum[1] + s_wsum[2] + s_wsum[3];
        atomicAdd(lossAcc, s);
    }
}

__global__ void vq_finalize(const float* __restrict__ lossAcc,
                            float* __restrict__ out)
{
    float m = lossAcc[0] * (1.0f / 4194304.0f);  // exact: /2^22
    out[4194304] = 0.25f * m + m;                // BETA*mse + mse, reference order
}

extern "C" void kernel_launch(void* const* d_in, const int* in_sizes, int n_in,
                              void* d_out, int out_size, void* d_ws, size_t ws_size,
                              hipStream_t stream)
{
    const float* x   = (const float*)d_in[0];   // [64,32,32,64] = 65536 x 64
    const float* emb = (const float*)d_in[1];   // [64,512]
    float* out = (float*)d_out;                 // 4194304 quantized_st + 1 loss
    float* acc = (float*)d_ws;

    hipMemsetAsync(acc, 0, sizeof(float), stream);
    vq_main<<<dim3(65536 / ROWS_PER_BLOCK), dim3(256), 0, stream>>>(x, emb, out, acc);
    vq_finalize<<<dim3(1), dim3(1), 0, stream>>>(acc, out);
}